// Round 1
// baseline (152.654 us; speedup 1.0000x reference)
//
#include <hip/hip_runtime.h>

// DiffGSTileSampler: depth-sorted gaussian alpha compositing, P=1024, 256x256 img.
// Record layout in d_ws (sorted by depth): [mx, my, ia, ib, ic, r, g, b] * P floats.

constexpr int P_GAUSS = 1024;
constexpr int IMG_H = 256;
constexpr int IMG_W = 256;

__global__ __launch_bounds__(1024) void gs_sort_prep(
    const float* __restrict__ means,   // P*2
    const float* __restrict__ covs,    // P*3
    const float* __restrict__ depth,   // P
    const float* __restrict__ colors,  // P*3
    float* __restrict__ recs)          // P*8 out
{
    __shared__ float sd[P_GAUSS];
    const int t = threadIdx.x;
    sd[t] = depth[t];
    __syncthreads();
    const float dt = sd[t];
    // stable rank sort: rank = #{j : d[j] < d[t] or (d[j]==d[t] and j<t)}
    int rank = 0;
    for (int j = 0; j < P_GAUSS; ++j) {
        float dj = sd[j];  // uniform address -> LDS broadcast
        rank += (dj < dt) || (dj == dt && j < t) ? 1 : 0;
    }
    const float a = covs[t * 3 + 0];
    const float b = covs[t * 3 + 1];
    const float c = covs[t * 3 + 2];
    const float det = a * c - b * b;
    const float ia = c / det;      // match reference: divides, not rcp-mul
    const float ib = -b / det;
    const float ic = a / det;
    float* r = recs + rank * 8;
    r[0] = means[t * 2 + 0];
    r[1] = means[t * 2 + 1];
    r[2] = ia;
    r[3] = ib;
    r[4] = ic;
    r[5] = colors[t * 3 + 0];
    r[6] = colors[t * 3 + 1];
    r[7] = colors[t * 3 + 2];
}

__global__ __launch_bounds__(256) void gs_render(
    const float* __restrict__ recs,   // P*8 sorted
    float* __restrict__ out)          // 3*H*W, chw
{
    __shared__ float g[P_GAUSS * 8];   // 32 KB
    const int tid = threadIdx.y * 16 + threadIdx.x;

    // stage all sorted records into LDS: 2048 float4, 8 per thread
    const float4* src = reinterpret_cast<const float4*>(recs);
    float4* dst = reinterpret_cast<float4*>(g);
#pragma unroll
    for (int i = 0; i < (P_GAUSS * 8 / 4) / 256; ++i)
        dst[tid + i * 256] = src[tid + i * 256];
    __syncthreads();

    const int x = blockIdx.x * 16 + threadIdx.x;
    const int y = blockIdx.y * 16 + threadIdx.y;
    const float px = (float)x + 0.5f;
    const float py = (float)y + 0.5f;

    float T = 1.0f;
    float cr = 0.0f, cg = 0.0f, cb = 0.0f;

    for (int p = 0; p < P_GAUSS; ++p) {
        const float* rp = g + p * 8;   // uniform address -> broadcast reads
        const float mx = rp[0], my = rp[1];
        const float ia = rp[2], ib = rp[3], ic = rp[4];
        const float dx = px - mx;
        const float dy = py - my;
        const float q = ia * dx * dx + 2.0f * ib * (dx * dy) + ic * dy * dy;
        // alpha < 1/255 iff q > 2*ln(255) = 11.0890; gate conservatively at 11.2
        if (q < 11.2f) {
            float alpha = fminf(0.99f, expf(-0.5f * q));
            if (alpha >= (1.0f / 255.0f)) {
                const float w = alpha * T;
                cr += w * rp[5];
                cg += w * rp[6];
                cb += w * rp[7];
                T *= (1.0f - alpha);
            }
        }
        if (__all(T < 6.1e-5f)) break;   // remaining contribution < 6.1e-5 << 2e-2 tol
    }

    const int pix = y * IMG_W + x;
    out[0 * IMG_H * IMG_W + pix] = cr;
    out[1 * IMG_H * IMG_W + pix] = cg;
    out[2 * IMG_H * IMG_W + pix] = cb;
}

extern "C" void kernel_launch(void* const* d_in, const int* in_sizes, int n_in,
                              void* d_out, int out_size, void* d_ws, size_t ws_size,
                              hipStream_t stream) {
    const float* means  = (const float*)d_in[0];
    const float* covs   = (const float*)d_in[1];
    const float* depth  = (const float*)d_in[2];
    const float* colors = (const float*)d_in[3];
    float* recs = (float*)d_ws;          // needs P*8*4 = 32 KB
    float* out  = (float*)d_out;

    gs_sort_prep<<<1, P_GAUSS, 0, stream>>>(means, covs, depth, colors, recs);
    gs_render<<<dim3(IMG_W / 16, IMG_H / 16), dim3(16, 16), 0, stream>>>(recs, out);
}

// Round 2
// 44.495 us; speedup vs baseline: 3.4308x; 3.4308x over previous
//
#include <hip/hip_runtime.h>

// DiffGSTileSampler: depth-sorted gaussian alpha compositing, P=1024, 256x256.
// d_ws layout: recs[P*8] floats (sorted records: mx,my,ia,ib,ic,r,g,b)
//              cullv[P]  float4 (mx,my,rx,ry) at offset P*8 floats.

constexpr int P_GAUSS = 1024;
constexpr int IMG_H = 256;
constexpr int IMG_W = 256;
constexpr float Q_GATE = 11.2f;   // alpha>=1/255 iff q<=2*ln255=11.0898; gate above it
constexpr float Q_CULL = 11.3f;   // cull radius margin above gate -> culling is exact

__global__ __launch_bounds__(256) void gs_prep(
    const float* __restrict__ means,   // P*2
    const float* __restrict__ covs,    // P*3
    const float* __restrict__ depth,   // P
    const float* __restrict__ colors,  // P*3
    float* __restrict__ recs,          // P*8 out (sorted)
    float4* __restrict__ cullv)        // P out (sorted)
{
    __shared__ float sd[P_GAUSS];
    const int tid = threadIdx.x;
    // stage all depths (each of 256 threads loads one float4)
    reinterpret_cast<float4*>(sd)[tid] = reinterpret_cast<const float4*>(depth)[tid];
    __syncthreads();

    const int t = blockIdx.x * 256 + tid;
    const float dt = sd[t];
    // stable rank: #{j : d[j] < d[t] || (d[j]==d[t] && j < t)}, float4-vectorized
    int rank = 0;
    const float4* sdv = reinterpret_cast<const float4*>(sd);
#pragma unroll 8
    for (int i = 0; i < P_GAUSS / 4; ++i) {
        const float4 d4 = sdv[i];
        const int j = 4 * i;
        rank += (d4.x < dt || (d4.x == dt && j + 0 < t)) ? 1 : 0;
        rank += (d4.y < dt || (d4.y == dt && j + 1 < t)) ? 1 : 0;
        rank += (d4.z < dt || (d4.z == dt && j + 2 < t)) ? 1 : 0;
        rank += (d4.w < dt || (d4.w == dt && j + 3 < t)) ? 1 : 0;
    }

    const float a = covs[t * 3 + 0];
    const float b = covs[t * 3 + 1];
    const float c = covs[t * 3 + 2];
    const float det = a * c - b * b;
    const float ia = c / det;      // match reference: divides
    const float ib = -b / det;
    const float ic = a / det;
    const float mx = means[t * 2 + 0];
    const float my = means[t * 2 + 1];

    float* r = recs + rank * 8;
    r[0] = mx;
    r[1] = my;
    r[2] = ia;
    r[3] = ib;
    r[4] = ic;
    r[5] = colors[t * 3 + 0];
    r[6] = colors[t * 3 + 1];
    r[7] = colors[t * 3 + 2];
    // bbox of {q <= Q_CULL}: half-extents sqrt(Q*Sigma_xx), sqrt(Q*Sigma_yy)
    cullv[rank] = make_float4(mx, my, sqrtf(Q_CULL * a), sqrtf(Q_CULL * c));
}

__global__ __launch_bounds__(256) void gs_render(
    const float* __restrict__ recs,    // P*8 sorted
    const float4* __restrict__ cullv,  // P sorted
    float* __restrict__ out)           // 3*H*W chw
{
    __shared__ float g[P_GAUSS * 8];   // compacted records (worst case all pass)
    __shared__ int cnt[4];

    const int tid = threadIdx.y * 16 + threadIdx.x;
    const int wid = tid >> 6;
    const int lane = tid & 63;

    // tile pixel-center bounds
    const float tx0 = (float)(blockIdx.x * 16) + 0.5f;
    const float tx1 = tx0 + 15.0f;
    const float ty0 = (float)(blockIdx.y * 16) + 0.5f;
    const float ty1 = ty0 + 15.0f;

    // preload this thread's 4 cull entries (one per round), coalesced
    float4 cv[4];
#pragma unroll
    for (int r = 0; r < 4; ++r) cv[r] = cullv[r * 256 + tid];

    // order-preserving stream compaction into LDS
    int total = 0;
#pragma unroll
    for (int r = 0; r < 4; ++r) {
        const float4 c = cv[r];
        const bool hit = (c.x + c.z >= tx0) && (c.x - c.z <= tx1) &&
                         (c.y + c.w >= ty0) && (c.y - c.w <= ty1);
        const unsigned long long m = __ballot(hit);
        if (lane == 0) cnt[wid] = __popcll(m);
        __syncthreads();
        int base = total;
        for (int w = 0; w < wid; ++w) base += cnt[w];
        if (hit) {
            const int slot = base + __popcll(m & ((1ull << lane) - 1ull));
            const int p = r * 256 + tid;
            const float4* src = reinterpret_cast<const float4*>(recs + p * 8);
            float4* dst = reinterpret_cast<float4*>(g + slot * 8);
            dst[0] = src[0];
            dst[1] = src[1];
        }
        total += cnt[0] + cnt[1] + cnt[2] + cnt[3];
        __syncthreads();   // record writes visible; cnt reusable next round
    }

    const float px = tx0 + (float)threadIdx.x;
    const float py = ty0 + (float)threadIdx.y;

    float T = 1.0f;
    float acr = 0.0f, acg = 0.0f, acb = 0.0f;

    // 2-deep software-pipelined composite over compacted list
    const float4* gv = reinterpret_cast<const float4*>(g);
    float4 ra, rb;
    if (total > 0) { ra = gv[0]; rb = gv[1]; }
    for (int p = 0; p < total; ++p) {
        const float4 c0 = ra;   // mx, my, ia, ib
        const float4 c1 = rb;   // ic, r, g, b
        if (p + 1 < total) { ra = gv[2 * (p + 1)]; rb = gv[2 * (p + 1) + 1]; }
        const float dx = px - c0.x;
        const float dy = py - c0.y;
        const float q = c0.z * dx * dx + 2.0f * c0.w * (dx * dy) + c1.x * dy * dy;
        if (q < Q_GATE) {
            const float alpha = fminf(0.99f, __expf(-0.5f * q));
            if (alpha >= (1.0f / 255.0f)) {
                const float w = alpha * T;
                acr += w * c1.y;
                acg += w * c1.z;
                acb += w * c1.w;
                T *= (1.0f - alpha);
            }
        }
    }

    const int pix = (blockIdx.y * 16 + threadIdx.y) * IMG_W + (blockIdx.x * 16 + threadIdx.x);
    out[0 * IMG_H * IMG_W + pix] = acr;
    out[1 * IMG_H * IMG_W + pix] = acg;
    out[2 * IMG_H * IMG_W + pix] = acb;
}

extern "C" void kernel_launch(void* const* d_in, const int* in_sizes, int n_in,
                              void* d_out, int out_size, void* d_ws, size_t ws_size,
                              hipStream_t stream) {
    const float* means  = (const float*)d_in[0];
    const float* covs   = (const float*)d_in[1];
    const float* depth  = (const float*)d_in[2];
    const float* colors = (const float*)d_in[3];
    float*  recs  = (float*)d_ws;                       // 32 KB
    float4* cullv = (float4*)((char*)d_ws + P_GAUSS * 8 * sizeof(float));  // +16 KB
    float*  out   = (float*)d_out;

    gs_prep<<<4, 256, 0, stream>>>(means, covs, depth, colors, recs, cullv);
    gs_render<<<dim3(IMG_W / 16, IMG_H / 16), dim3(16, 16), 0, stream>>>(recs, cullv, out);
}

// Round 3
// 16.563 us; speedup vs baseline: 9.2165x; 2.6864x over previous
//
#include <hip/hip_runtime.h>

// DiffGSTileSampler, fully fused single kernel.
// Per 16x16 tile: cull 1024 gaussians -> compact survivors to LDS (orig order)
// -> rank-sort survivors by (depth, orig index) -> invert cov -> composite.
// Sorting after culling is exact: compositing order only matters among
// gaussians that contribute (alpha>=1/255 <=> q<=11.09 < cull radius 11.3).

constexpr int P_GAUSS = 1024;
constexpr int IMG_H = 256;
constexpr int IMG_W = 256;
constexpr float Q_GATE = 11.2f;   // alpha>=1/255 iff q<=2*ln255=11.0898
constexpr float Q_CULL = 11.3f;   // conservative bbox level-set -> culling exact

__global__ __launch_bounds__(256) void gs_fused(
    const float* __restrict__ means,   // P*2
    const float* __restrict__ covs,    // P*3
    const float* __restrict__ depth,   // P
    const float* __restrict__ colors,  // P*3
    float* __restrict__ out)           // 3*H*W chw
{
    __shared__ float g[P_GAUSS * 8];     // survivor records, compaction (=orig) order
    __shared__ float sdepth[P_GAUSS];    // survivor depths
    __shared__ int   sperm[P_GAUSS];     // sorted pos -> slot
    __shared__ int   cnt16[16];          // per (round, wave) hit counts

    const int tid = threadIdx.y * 16 + threadIdx.x;
    const int wid = tid >> 6;
    const int lane = tid & 63;

    const float tx0 = (float)(blockIdx.x * 16) + 0.5f;
    const float tx1 = tx0 + 15.0f;
    const float ty0 = (float)(blockIdx.y * 16) + 0.5f;
    const float ty1 = ty0 + 15.0f;

    // ---- load 4 gaussians/thread, cull, ballot ----
    float mx[4], my[4], ca[4], cb[4], cc[4], dp[4], cr[4], cg[4], cbl[4];
    unsigned long long msk[4];
    bool hit[4];
#pragma unroll
    for (int r = 0; r < 4; ++r) {
        const int p = r * 256 + tid;
        const float2 m2 = reinterpret_cast<const float2*>(means)[p];
        mx[r] = m2.x; my[r] = m2.y;
        ca[r] = covs[p * 3 + 0];
        cb[r] = covs[p * 3 + 1];
        cc[r] = covs[p * 3 + 2];
        dp[r] = depth[p];
        cr[r] = colors[p * 3 + 0];
        cg[r] = colors[p * 3 + 1];
        cbl[r] = colors[p * 3 + 2];
        const float rx = sqrtf(Q_CULL * ca[r]);   // half-extent of {q<=Q} in x
        const float ry = sqrtf(Q_CULL * cc[r]);
        hit[r] = (mx[r] + rx >= tx0) && (mx[r] - rx <= tx1) &&
                 (my[r] + ry >= ty0) && (my[r] - ry <= ty1);
        msk[r] = __ballot(hit[r]);
        if (lane == 0) cnt16[r * 4 + wid] = __popcll(msk[r]);
    }
    __syncthreads();

    // exclusive prefix over the 16 (round-major, wave-minor) counts
    int c16[16];
#pragma unroll
    for (int k = 0; k < 16; ++k) c16[k] = cnt16[k];
    int total = 0;
#pragma unroll
    for (int k = 0; k < 16; ++k) total += c16[k];

#pragma unroll
    for (int r = 0; r < 4; ++r) {
        if (hit[r]) {
            const int key = r * 4 + wid;
            int base = 0;
            for (int k = 0; k < key; ++k) base += c16[k];
            const int slot = base + __popcll(msk[r] & ((1ull << lane) - 1ull));
            float* rec = g + slot * 8;
            rec[0] = mx[r]; rec[1] = my[r];
            rec[2] = ca[r]; rec[3] = cb[r]; rec[4] = cc[r];
            rec[5] = cr[r]; rec[6] = cg[r]; rec[7] = cbl[r];
            sdepth[slot] = dp[r];
        }
    }
    __syncthreads();

    // ---- rank-sort survivors by (depth, slot) ; invert covariance in place ----
    for (int s = tid; s < total; s += 256) {
        const float d = sdepth[s];
        int rank = 0;
        for (int j = 0; j < total; ++j) {
            const float dj = sdepth[j];         // uniform addr -> LDS broadcast
            rank += (dj < d || (dj == d && j < s)) ? 1 : 0;
        }
        sperm[rank] = s;
        const float a = g[s * 8 + 2];
        const float b = g[s * 8 + 3];
        const float c = g[s * 8 + 4];
        const float det = a * c - b * b;
        g[s * 8 + 2] = c / det;                 // divides: match reference
        g[s * 8 + 3] = -b / det;
        g[s * 8 + 4] = a / det;
    }
    __syncthreads();

    // ---- composite front-to-back ----
    const float px = tx0 + (float)threadIdx.x;
    const float py = ty0 + (float)threadIdx.y;

    float T = 1.0f;
    float acr = 0.0f, acg = 0.0f, acb = 0.0f;

    const float4* gv = reinterpret_cast<const float4*>(g);
    float4 ra, rb;
    int slN = 0;
    if (total > 0) {
        const int s0 = sperm[0];
        ra = gv[2 * s0]; rb = gv[2 * s0 + 1];
        if (total > 1) slN = sperm[1];
    }
    for (int p = 0; p < total; ++p) {
        const float4 c0 = ra;   // mx, my, ia, ib
        const float4 c1 = rb;   // ic, r, g, b
        if (p + 1 < total) { ra = gv[2 * slN]; rb = gv[2 * slN + 1]; }
        if (p + 2 < total) slN = sperm[p + 2];
        const float dx = px - c0.x;
        const float dy = py - c0.y;
        const float q = c0.z * dx * dx + 2.0f * c0.w * (dx * dy) + c1.x * dy * dy;
        if (q < Q_GATE) {
            const float alpha = fminf(0.99f, __expf(-0.5f * q));
            if (alpha >= (1.0f / 255.0f)) {
                const float w = alpha * T;
                acr += w * c1.y;
                acg += w * c1.z;
                acb += w * c1.w;
                T *= (1.0f - alpha);
            }
        }
    }

    const int pix = (blockIdx.y * 16 + threadIdx.y) * IMG_W + (blockIdx.x * 16 + threadIdx.x);
    out[0 * IMG_H * IMG_W + pix] = acr;
    out[1 * IMG_H * IMG_W + pix] = acg;
    out[2 * IMG_H * IMG_W + pix] = acb;
}

extern "C" void kernel_launch(void* const* d_in, const int* in_sizes, int n_in,
                              void* d_out, int out_size, void* d_ws, size_t ws_size,
                              hipStream_t stream) {
    const float* means  = (const float*)d_in[0];
    const float* covs   = (const float*)d_in[1];
    const float* depth  = (const float*)d_in[2];
    const float* colors = (const float*)d_in[3];
    float* out = (float*)d_out;

    gs_fused<<<dim3(IMG_W / 16, IMG_H / 16), dim3(16, 16), 0, stream>>>(
        means, covs, depth, colors, out);
}

// Round 4
// 15.117 us; speedup vs baseline: 10.0982x; 1.0957x over previous
//
#include <hip/hip_runtime.h>
#include <cfloat>

// DiffGSTileSampler, fused single kernel.
// Per 16x16 tile: stage raw inputs to LDS (coalesced) -> cull 1024 gaussians
// -> ballot-compact survivors (orig order) -> rank-sort by (depth, orig idx),
// writing inverted records directly into sorted order -> linear composite.
// Culling is exact: contribution requires q <= 11.09 < cull level 11.3.

constexpr int P_GAUSS = 1024;
constexpr int IMG_H = 256;
constexpr int IMG_W = 256;
constexpr float Q_GATE = 11.2f;   // alpha>=1/255 iff q<=2*ln255=11.0898
constexpr float Q_CULL = 11.3f;

// raw staging layout (float offsets)
constexpr int RAW_MEANS = 0;      // 2048 floats
constexpr int RAW_COVS  = 2048;   // 3072
constexpr int RAW_DEPTH = 5120;   // 1024
constexpr int RAW_COLS  = 6144;   // 3072
constexpr int RAW_TOT   = 9216;   // 36 KB

__global__ __launch_bounds__(256) void gs_fused(
    const float* __restrict__ means,   // P*2
    const float* __restrict__ covs,    // P*3
    const float* __restrict__ depth,   // P
    const float* __restrict__ colors,  // P*3
    float* __restrict__ out)           // 3*H*W chw
{
    __shared__ float rawbuf[RAW_TOT];       // later aliased by g2 (sorted recs)
    __shared__ float g[P_GAUSS * 8];        // compacted records, orig order
    __shared__ float sdepth[P_GAUSS + 4];   // survivor depths (+pad)
    __shared__ int   cnt16[16];

    float* const g2 = rawbuf;               // alias: raw is dead after phase 2

    const int tid = threadIdx.y * 16 + threadIdx.x;
    const int wid = tid >> 6;
    const int lane = tid & 63;

    // ---- phase 1: coalesced float4 staging of all inputs ----
    {
        float4* rv = reinterpret_cast<float4*>(rawbuf);
        const float4* mv = reinterpret_cast<const float4*>(means);
        const float4* cv = reinterpret_cast<const float4*>(covs);
        const float4* dv = reinterpret_cast<const float4*>(depth);
        const float4* lv = reinterpret_cast<const float4*>(colors);
        rv[RAW_MEANS / 4 + tid]       = mv[tid];
        rv[RAW_MEANS / 4 + 256 + tid] = mv[256 + tid];
        rv[RAW_COVS / 4 + tid]        = cv[tid];
        rv[RAW_COVS / 4 + 256 + tid]  = cv[256 + tid];
        rv[RAW_COVS / 4 + 512 + tid]  = cv[512 + tid];
        rv[RAW_DEPTH / 4 + tid]       = dv[tid];
        rv[RAW_COLS / 4 + tid]        = lv[tid];
        rv[RAW_COLS / 4 + 256 + tid]  = lv[256 + tid];
        rv[RAW_COLS / 4 + 512 + tid]  = lv[512 + tid];
    }
    __syncthreads();

    const float tx0 = (float)(blockIdx.x * 16) + 0.5f;
    const float tx1 = tx0 + 15.0f;
    const float ty0 = (float)(blockIdx.y * 16) + 0.5f;
    const float ty1 = ty0 + 15.0f;

    // ---- phase 2: registers <- LDS raw; cull; ballot counts ----
    float mx[4], my[4], ca[4], cb[4], cc[4], dp[4], cr[4], cg[4], cbl[4];
    unsigned long long msk[4];
    bool hit[4];
#pragma unroll
    for (int r = 0; r < 4; ++r) {
        const int p = r * 256 + tid;
        const float2 m2 = reinterpret_cast<const float2*>(rawbuf + RAW_MEANS)[p];
        mx[r] = m2.x; my[r] = m2.y;
        ca[r]  = rawbuf[RAW_COVS + 3 * p + 0];
        cb[r]  = rawbuf[RAW_COVS + 3 * p + 1];
        cc[r]  = rawbuf[RAW_COVS + 3 * p + 2];
        dp[r]  = rawbuf[RAW_DEPTH + p];
        cr[r]  = rawbuf[RAW_COLS + 3 * p + 0];
        cg[r]  = rawbuf[RAW_COLS + 3 * p + 1];
        cbl[r] = rawbuf[RAW_COLS + 3 * p + 2];
        const float rx = sqrtf(Q_CULL * ca[r]);
        const float ry = sqrtf(Q_CULL * cc[r]);
        hit[r] = (mx[r] + rx >= tx0) && (mx[r] - rx <= tx1) &&
                 (my[r] + ry >= ty0) && (my[r] - ry <= ty1);
        msk[r] = __ballot(hit[r]);
        if (lane == 0) cnt16[r * 4 + wid] = __popcll(msk[r]);
    }
    __syncthreads();   // raw fully consumed into registers; cnt16 visible

    int c16[16];
#pragma unroll
    for (int k = 0; k < 16; ++k) c16[k] = cnt16[k];
    int total = 0;
#pragma unroll
    for (int k = 0; k < 16; ++k) total += c16[k];

    // ---- phase 3: scatter survivors (orig order) + depth; pad depths ----
#pragma unroll
    for (int r = 0; r < 4; ++r) {
        if (hit[r]) {
            const int key = r * 4 + wid;
            int base = 0;
            for (int k = 0; k < key; ++k) base += c16[k];
            const int slot = base + __popcll(msk[r] & ((1ull << lane) - 1ull));
            float4* rec = reinterpret_cast<float4*>(g + slot * 8);
            rec[0] = make_float4(mx[r], my[r], ca[r], cb[r]);
            rec[1] = make_float4(cc[r], cr[r], cg[r], cbl[r]);
            sdepth[slot] = dp[r];
        }
    }
    if (tid < 4) sdepth[total + tid] = FLT_MAX;   // pad for float4 rank loop
    __syncthreads();

    // ---- phase 4: rank-sort; write inverted record at sorted position ----
    const int limit4 = (total + 3) >> 2;
    for (int s = tid; s < total; s += 256) {
        const float d = sdepth[s];
        int rank = 0;
        const float4* sd4 = reinterpret_cast<const float4*>(sdepth);
        for (int jj = 0; jj < limit4; ++jj) {
            const float4 d4 = sd4[jj];
            const int j = 4 * jj;
            rank += (d4.x < d || (d4.x == d && j + 0 < s)) ? 1 : 0;
            rank += (d4.y < d || (d4.y == d && j + 1 < s)) ? 1 : 0;
            rank += (d4.z < d || (d4.z == d && j + 2 < s)) ? 1 : 0;
            rank += (d4.w < d || (d4.w == d && j + 3 < s)) ? 1 : 0;
        }
        const float4 r0 = reinterpret_cast<const float4*>(g + s * 8)[0]; // mx,my,a,b
        const float4 r1 = reinterpret_cast<const float4*>(g + s * 8)[1]; // c,r,g,b
        const float a = r0.z, b = r0.w, c = r1.x;
        const float det = a * c - b * b;
        float4* dst = reinterpret_cast<float4*>(g2 + rank * 8);
        dst[0] = make_float4(r0.x, r0.y, c / det, -b / det);   // mx,my,ia,ib
        dst[1] = make_float4(a / det, r1.y, r1.z, r1.w);       // ic,r,g,b
    }
    __syncthreads();

    // ---- phase 5: linear front-to-back composite, 2-deep prefetch ----
    const float px = tx0 + (float)threadIdx.x;
    const float py = ty0 + (float)threadIdx.y;

    float T = 1.0f;
    float acr = 0.0f, acg = 0.0f, acb = 0.0f;

    const float4* gv = reinterpret_cast<const float4*>(g2);
    float4 A0, B0, A1, B1;
    if (total > 0) { A0 = gv[0]; B0 = gv[1]; }
    if (total > 1) { A1 = gv[2]; B1 = gv[3]; }
    for (int p = 0; p < total; ++p) {
        const float4 c0 = A0;   // mx, my, ia, ib
        const float4 c1 = B0;   // ic, r, g, b
        A0 = A1; B0 = B1;
        if (p + 2 < total) { A1 = gv[2 * p + 4]; B1 = gv[2 * p + 5]; }
        const float dx = px - c0.x;
        const float dy = py - c0.y;
        const float q = c0.z * dx * dx + 2.0f * c0.w * (dx * dy) + c1.x * dy * dy;
        if (q < Q_GATE) {
            const float alpha = fminf(0.99f, __expf(-0.5f * q));
            if (alpha >= (1.0f / 255.0f)) {
                const float w = alpha * T;
                acr += w * c1.y;
                acg += w * c1.z;
                acb += w * c1.w;
                T *= (1.0f - alpha);
            }
        }
    }

    const int pix = (blockIdx.y * 16 + threadIdx.y) * IMG_W + (blockIdx.x * 16 + threadIdx.x);
    out[0 * IMG_H * IMG_W + pix] = acr;
    out[1 * IMG_H * IMG_W + pix] = acg;
    out[2 * IMG_H * IMG_W + pix] = acb;
}

extern "C" void kernel_launch(void* const* d_in, const int* in_sizes, int n_in,
                              void* d_out, int out_size, void* d_ws, size_t ws_size,
                              hipStream_t stream) {
    const float* means  = (const float*)d_in[0];
    const float* covs   = (const float*)d_in[1];
    const float* depth  = (const float*)d_in[2];
    const float* colors = (const float*)d_in[3];
    float* out = (float*)d_out;

    gs_fused<<<dim3(IMG_W / 16, IMG_H / 16), dim3(16, 16), 0, stream>>>(
        means, covs, depth, colors, out);
}

// Round 5
// 14.944 us; speedup vs baseline: 10.2149x; 1.0116x over previous
//
#include <hip/hip_runtime.h>
#include <cfloat>

// DiffGSTileSampler, fused single kernel.
// Per 16x16 tile: stage raw inputs to LDS (coalesced) -> cull 1024 gaussians
// (reading only mx,my,a,c) -> ballot-compact survivors, gathering the
// remaining fields (b, depth, rgb) only for hits -> rank-sort by
// (depth, orig idx), writing inverted records into sorted order -> linear
// branchless composite. Culling exact: contribution needs q<=11.09<11.3.

constexpr int P_GAUSS = 1024;
constexpr int IMG_H = 256;
constexpr int IMG_W = 256;
constexpr float Q_GATE = 11.2f;   // alpha>=1/255 iff q<=2*ln255=11.0898
constexpr float Q_CULL = 11.3f;

// raw staging layout (float offsets)
constexpr int RAW_MEANS = 0;      // 2048 floats
constexpr int RAW_COVS  = 2048;   // 3072
constexpr int RAW_DEPTH = 5120;   // 1024
constexpr int RAW_COLS  = 6144;   // 3072
constexpr int RAW_TOT   = 9216;   // 36 KB

__global__ __launch_bounds__(256) void gs_fused(
    const float* __restrict__ means,   // P*2
    const float* __restrict__ covs,    // P*3
    const float* __restrict__ depth,   // P
    const float* __restrict__ colors,  // P*3
    float* __restrict__ out)           // 3*H*W chw
{
    __shared__ float rawbuf[RAW_TOT];       // later aliased by g2 (sorted recs)
    __shared__ float g[P_GAUSS * 8];        // compacted records, orig order
    __shared__ float sdepth[P_GAUSS + 4];   // survivor depths (+pad)
    __shared__ int   cnt16[16];

    float* const g2 = rawbuf;               // alias: raw is dead before phase-4 writes

    const int tid = threadIdx.y * 16 + threadIdx.x;
    const int wid = tid >> 6;
    const int lane = tid & 63;

    // ---- phase 1: coalesced float4 staging of all inputs ----
    {
        float4* rv = reinterpret_cast<float4*>(rawbuf);
        const float4* mv = reinterpret_cast<const float4*>(means);
        const float4* cv = reinterpret_cast<const float4*>(covs);
        const float4* dv = reinterpret_cast<const float4*>(depth);
        const float4* lv = reinterpret_cast<const float4*>(colors);
        rv[RAW_MEANS / 4 + tid]       = mv[tid];
        rv[RAW_MEANS / 4 + 256 + tid] = mv[256 + tid];
        rv[RAW_COVS / 4 + tid]        = cv[tid];
        rv[RAW_COVS / 4 + 256 + tid]  = cv[256 + tid];
        rv[RAW_COVS / 4 + 512 + tid]  = cv[512 + tid];
        rv[RAW_DEPTH / 4 + tid]       = dv[tid];
        rv[RAW_COLS / 4 + tid]        = lv[tid];
        rv[RAW_COLS / 4 + 256 + tid]  = lv[256 + tid];
        rv[RAW_COLS / 4 + 512 + tid]  = lv[512 + tid];
    }
    __syncthreads();

    const float tx0 = (float)(blockIdx.x * 16) + 0.5f;
    const float tx1 = tx0 + 15.0f;
    const float ty0 = (float)(blockIdx.y * 16) + 0.5f;
    const float ty1 = ty0 + 15.0f;

    // ---- phase 2: cull (reads only mx,my,a,c); ballot counts ----
    float mx[4], my[4], ca[4], cc[4];
    unsigned long long msk[4];
    bool hit[4];
#pragma unroll
    for (int r = 0; r < 4; ++r) {
        const int p = r * 256 + tid;
        const float2 m2 = reinterpret_cast<const float2*>(rawbuf + RAW_MEANS)[p];
        mx[r] = m2.x; my[r] = m2.y;
        ca[r] = rawbuf[RAW_COVS + 3 * p + 0];
        cc[r] = rawbuf[RAW_COVS + 3 * p + 2];
        const float rx = sqrtf(Q_CULL * ca[r]);
        const float ry = sqrtf(Q_CULL * cc[r]);
        hit[r] = (mx[r] + rx >= tx0) && (mx[r] - rx <= tx1) &&
                 (my[r] + ry >= ty0) && (my[r] - ry <= ty1);
        msk[r] = __ballot(hit[r]);
        if (lane == 0) cnt16[r * 4 + wid] = __popcll(msk[r]);
    }
    __syncthreads();

    int c16[16];
#pragma unroll
    for (int k = 0; k < 16; ++k) c16[k] = cnt16[k];
    int total = 0;
#pragma unroll
    for (int k = 0; k < 16; ++k) total += c16[k];

    // ---- phase 3: scatter survivors; gather remaining fields for hits only ----
#pragma unroll
    for (int r = 0; r < 4; ++r) {
        if (hit[r]) {
            const int p = r * 256 + tid;
            const float cb  = rawbuf[RAW_COVS + 3 * p + 1];
            const float dp  = rawbuf[RAW_DEPTH + p];
            const float cr  = rawbuf[RAW_COLS + 3 * p + 0];
            const float cg  = rawbuf[RAW_COLS + 3 * p + 1];
            const float cbl = rawbuf[RAW_COLS + 3 * p + 2];
            const int key = r * 4 + wid;
            int base = 0;
            for (int k = 0; k < key; ++k) base += c16[k];
            const int slot = base + __popcll(msk[r] & ((1ull << lane) - 1ull));
            float4* rec = reinterpret_cast<float4*>(g + slot * 8);
            rec[0] = make_float4(mx[r], my[r], ca[r], cb);
            rec[1] = make_float4(cc[r], cr, cg, cbl);
            sdepth[slot] = dp;
        }
    }
    if (tid < 4) sdepth[total + tid] = FLT_MAX;   // pad for float4 rank loop
    __syncthreads();

    // ---- phase 4: rank-sort; write inverted record at sorted position ----
    const int limit4 = (total + 3) >> 2;
    for (int s = tid; s < total; s += 256) {
        const float d = sdepth[s];
        int rank = 0;
        const float4* sd4 = reinterpret_cast<const float4*>(sdepth);
        for (int jj = 0; jj < limit4; ++jj) {
            const float4 d4 = sd4[jj];
            const int j = 4 * jj;
            rank += (d4.x < d || (d4.x == d && j + 0 < s)) ? 1 : 0;
            rank += (d4.y < d || (d4.y == d && j + 1 < s)) ? 1 : 0;
            rank += (d4.z < d || (d4.z == d && j + 2 < s)) ? 1 : 0;
            rank += (d4.w < d || (d4.w == d && j + 3 < s)) ? 1 : 0;
        }
        const float4 r0 = reinterpret_cast<const float4*>(g + s * 8)[0]; // mx,my,a,b
        const float4 r1 = reinterpret_cast<const float4*>(g + s * 8)[1]; // c,r,g,b
        const float a = r0.z, b = r0.w, c = r1.x;
        const float inv = 1.0f / (a * c - b * b);   // 1 divide + 3 muls (<=1 ulp vs ref)
        float4* dst = reinterpret_cast<float4*>(g2 + rank * 8);
        dst[0] = make_float4(r0.x, r0.y, c * inv, -b * inv);   // mx,my,ia,ib
        dst[1] = make_float4(a * inv, r1.y, r1.z, r1.w);       // ic,r,g,b
    }
    __syncthreads();

    // ---- phase 5: linear front-to-back composite, branchless, 2-deep prefetch ----
    const float px = tx0 + (float)threadIdx.x;
    const float py = ty0 + (float)threadIdx.y;

    float T = 1.0f;
    float acr = 0.0f, acg = 0.0f, acb = 0.0f;

    const float4* gv = reinterpret_cast<const float4*>(g2);
    float4 A0, B0, A1, B1;
    if (total > 0) { A0 = gv[0]; B0 = gv[1]; }
    if (total > 1) { A1 = gv[2]; B1 = gv[3]; }
    for (int p = 0; p < total; ++p) {
        const float4 c0 = A0;   // mx, my, ia, ib
        const float4 c1 = B0;   // ic, r, g, b
        A0 = A1; B0 = B1;
        if (p + 2 < total) { A1 = gv[2 * p + 4]; B1 = gv[2 * p + 5]; }
        const float dx = px - c0.x;
        const float dy = py - c0.y;
        const float q = c0.z * dx * dx + 2.0f * c0.w * (dx * dy) + c1.x * dy * dy;
        float alpha = fminf(0.99f, __expf(-0.5f * q));
        alpha = (q < Q_GATE && alpha >= (1.0f / 255.0f)) ? alpha : 0.0f;
        const float w = alpha * T;
        acr += w * c1.y;
        acg += w * c1.z;
        acb += w * c1.w;
        T *= (1.0f - alpha);
    }

    const int pix = (blockIdx.y * 16 + threadIdx.y) * IMG_W + (blockIdx.x * 16 + threadIdx.x);
    out[0 * IMG_H * IMG_W + pix] = acr;
    out[1 * IMG_H * IMG_W + pix] = acg;
    out[2 * IMG_H * IMG_W + pix] = acb;
}

extern "C" void kernel_launch(void* const* d_in, const int* in_sizes, int n_in,
                              void* d_out, int out_size, void* d_ws, size_t ws_size,
                              hipStream_t stream) {
    const float* means  = (const float*)d_in[0];
    const float* covs   = (const float*)d_in[1];
    const float* depth  = (const float*)d_in[2];
    const float* colors = (const float*)d_in[3];
    float* out = (float*)d_out;

    gs_fused<<<dim3(IMG_W / 16, IMG_H / 16), dim3(16, 16), 0, stream>>>(
        means, covs, depth, colors, out);
}

// Round 6
// 13.703 us; speedup vs baseline: 11.1401x; 1.0906x over previous
//
#include <hip/hip_runtime.h>
#include <cfloat>

// DiffGSTileSampler, fused single kernel, 512 threads/block.
// Per 16x16 tile: cull 1024 gaussians straight from global (means float2 +
// a,c scalars; all L2-resident) while staging covs/depth/colors to LDS ->
// ballot-compact survivors (original order) -> rank-sort by (depth, orig idx)
// writing inverted records into sorted order -> linear branchless composite
// on the first 256 threads. Culling exact: contribution needs q<=11.09<11.3.

constexpr int P_GAUSS = 1024;
constexpr int IMG_H = 256;
constexpr int IMG_W = 256;
constexpr float Q_GATE = 11.2f;   // alpha>=1/255 iff q<=2*ln255=11.0898
constexpr float Q_CULL = 11.3f;

// staged-raw layout (float offsets): covs | depth | colors
constexpr int RAW_COVS  = 0;      // 3072 floats
constexpr int RAW_DEPTH = 3072;   // 1024
constexpr int RAW_COLS  = 4096;   // 3072
constexpr int RAW_TOT   = 7168;   // 28 KB

__global__ __launch_bounds__(512) void gs_fused(
    const float* __restrict__ means,   // P*2
    const float* __restrict__ covs,    // P*3
    const float* __restrict__ depth,   // P
    const float* __restrict__ colors,  // P*3
    float* __restrict__ out)           // 3*H*W chw
{
    __shared__ float rawbuf[RAW_TOT];       // hit-gather fields
    __shared__ float g[P_GAUSS * 8];        // compacted records, orig order
    __shared__ float g2[P_GAUSS * 8];       // sorted inverted records
    __shared__ float sdepth[P_GAUSS + 4];   // survivor depths (+pad)
    __shared__ int   cnt16[16];

    const int tid = threadIdx.x;
    const int wid = tid >> 6;
    const int lane = tid & 63;

    const float tx0 = (float)(blockIdx.x * 16) + 0.5f;
    const float tx1 = tx0 + 15.0f;
    const float ty0 = (float)(blockIdx.y * 16) + 0.5f;
    const float ty1 = ty0 + 15.0f;

    // ---- staging of hit-gather fields (concurrent with cull loads) ----
    {
        float4* rv = reinterpret_cast<float4*>(rawbuf);
        const float4* cv = reinterpret_cast<const float4*>(covs);
        const float4* dv = reinterpret_cast<const float4*>(depth);
        const float4* lv = reinterpret_cast<const float4*>(colors);
        rv[RAW_COVS / 4 + tid] = cv[tid];
        rv[RAW_COLS / 4 + tid] = lv[tid];
        if (tid < 256) {
            rv[RAW_COVS / 4 + 512 + tid] = cv[512 + tid];
            rv[RAW_COLS / 4 + 512 + tid] = lv[512 + tid];
            rv[RAW_DEPTH / 4 + tid]      = dv[tid];
        }
    }

    // ---- cull directly from global; ballot counts ----
    float mx[2], my[2], ca[2], cc[2];
    unsigned long long msk[2];
    bool hit[2];
#pragma unroll
    for (int r = 0; r < 2; ++r) {
        const int p = r * 512 + tid;
        const float2 m2 = reinterpret_cast<const float2*>(means)[p];
        mx[r] = m2.x; my[r] = m2.y;
        ca[r] = covs[3 * p + 0];
        cc[r] = covs[3 * p + 2];
        const float rx = sqrtf(Q_CULL * ca[r]);
        const float ry = sqrtf(Q_CULL * cc[r]);
        hit[r] = (mx[r] + rx >= tx0) && (mx[r] - rx <= tx1) &&
                 (my[r] + ry >= ty0) && (my[r] - ry <= ty1);
        msk[r] = __ballot(hit[r]);
        if (lane == 0) cnt16[r * 8 + wid] = __popcll(msk[r]);
    }
    __syncthreads();   // cnt16 visible; staging ds_writes complete

    int c16[16];
#pragma unroll
    for (int k = 0; k < 16; ++k) c16[k] = cnt16[k];
    int total = 0;
#pragma unroll
    for (int k = 0; k < 16; ++k) total += c16[k];

    // ---- scatter survivors; gather remaining fields (hits only, from LDS) ----
#pragma unroll
    for (int r = 0; r < 2; ++r) {
        if (hit[r]) {
            const int p = r * 512 + tid;
            const float cb  = rawbuf[RAW_COVS + 3 * p + 1];
            const float dp  = rawbuf[RAW_DEPTH + p];
            const float cr  = rawbuf[RAW_COLS + 3 * p + 0];
            const float cg  = rawbuf[RAW_COLS + 3 * p + 1];
            const float cbl = rawbuf[RAW_COLS + 3 * p + 2];
            const int key = r * 8 + wid;
            int base = 0;
            for (int k = 0; k < key; ++k) base += c16[k];
            const int slot = base + __popcll(msk[r] & ((1ull << lane) - 1ull));
            float4* rec = reinterpret_cast<float4*>(g + slot * 8);
            rec[0] = make_float4(mx[r], my[r], ca[r], cb);
            rec[1] = make_float4(cc[r], cr, cg, cbl);
            sdepth[slot] = dp;
        }
    }
    if (tid < 4) sdepth[total + tid] = FLT_MAX;   // pad for float4 rank loop
    __syncthreads();

    // ---- rank-sort; write inverted record at sorted position ----
    const int limit4 = (total + 3) >> 2;
    for (int s = tid; s < total; s += 512) {
        const float d = sdepth[s];
        int rank = 0;
        const float4* sd4 = reinterpret_cast<const float4*>(sdepth);
        for (int jj = 0; jj < limit4; ++jj) {
            const float4 d4 = sd4[jj];
            const int j = 4 * jj;
            rank += (d4.x < d || (d4.x == d && j + 0 < s)) ? 1 : 0;
            rank += (d4.y < d || (d4.y == d && j + 1 < s)) ? 1 : 0;
            rank += (d4.z < d || (d4.z == d && j + 2 < s)) ? 1 : 0;
            rank += (d4.w < d || (d4.w == d && j + 3 < s)) ? 1 : 0;
        }
        const float4 r0 = reinterpret_cast<const float4*>(g + s * 8)[0]; // mx,my,a,b
        const float4 r1 = reinterpret_cast<const float4*>(g + s * 8)[1]; // c,r,g,b
        const float a = r0.z, b = r0.w, c = r1.x;
        const float inv = 1.0f / (a * c - b * b);
        float4* dst = reinterpret_cast<float4*>(g2 + rank * 8);
        dst[0] = make_float4(r0.x, r0.y, c * inv, -b * inv);   // mx,my,ia,ib
        dst[1] = make_float4(a * inv, r1.y, r1.z, r1.w);       // ic,r,g,b
    }
    __syncthreads();

    // ---- linear front-to-back composite (first 256 threads = 16x16 pixels) ----
    if (tid < 256) {
        const float px = tx0 + (float)(tid & 15);
        const float py = ty0 + (float)(tid >> 4);

        float T = 1.0f;
        float acr = 0.0f, acg = 0.0f, acb = 0.0f;

        const float4* gv = reinterpret_cast<const float4*>(g2);
        float4 A0, B0, A1, B1;
        if (total > 0) { A0 = gv[0]; B0 = gv[1]; }
        if (total > 1) { A1 = gv[2]; B1 = gv[3]; }
        for (int p = 0; p < total; ++p) {
            const float4 c0 = A0;   // mx, my, ia, ib
            const float4 c1 = B0;   // ic, r, g, b
            A0 = A1; B0 = B1;
            if (p + 2 < total) { A1 = gv[2 * p + 4]; B1 = gv[2 * p + 5]; }
            const float dx = px - c0.x;
            const float dy = py - c0.y;
            const float q = c0.z * dx * dx + 2.0f * c0.w * (dx * dy) + c1.x * dy * dy;
            float alpha = fminf(0.99f, __expf(-0.5f * q));
            alpha = (q < Q_GATE && alpha >= (1.0f / 255.0f)) ? alpha : 0.0f;
            const float w = alpha * T;
            acr += w * c1.y;
            acg += w * c1.z;
            acb += w * c1.w;
            T *= (1.0f - alpha);
        }

        const int pix = (blockIdx.y * 16 + (tid >> 4)) * IMG_W + (blockIdx.x * 16 + (tid & 15));
        out[0 * IMG_H * IMG_W + pix] = acr;
        out[1 * IMG_H * IMG_W + pix] = acg;
        out[2 * IMG_H * IMG_W + pix] = acb;
    }
}

extern "C" void kernel_launch(void* const* d_in, const int* in_sizes, int n_in,
                              void* d_out, int out_size, void* d_ws, size_t ws_size,
                              hipStream_t stream) {
    const float* means  = (const float*)d_in[0];
    const float* covs   = (const float*)d_in[1];
    const float* depth  = (const float*)d_in[2];
    const float* colors = (const float*)d_in[3];
    float* out = (float*)d_out;

    gs_fused<<<dim3(IMG_W / 16, IMG_H / 16), dim3(512), 0, stream>>>(
        means, covs, depth, colors, out);
}